// Round 2
// baseline (167.386 us; speedup 1.0000x reference)
//
#include <hip/hip_runtime.h>
#include <hip/hip_bf16.h>

// out[i] = 10 * min_j ||x_i - y_j||, x: 8192x96 f32, y: 65536x96 f32.
// sq = x2[i] + (y2[j] - 2*x.y): bf16 MFMA computes (y2 - 2*x.y) by pre-scaling
// train by -2 (exact in bf16) and preloading y2 as the MFMA C operand.
// R8: R7 (32x32x16 MFMA: 2382 vs 2075 TF ceiling) with the ONE unverified
//     ingredient removed: the v_min3_f32 inline asm is replaced by a plain
//     fminf balanced tree (one-delta experiment; all layout facts cross-
//     confirmed vs m74/m101 C/D formula + m214 attn's refcheck'd mfma(K,Q)
//     convention: first-op rows = (reg&3)+8*(reg>>2)+4*hi, second-op cols =
//     lane&31, A/B k-maps symmetric so any consistent k-permutation is exact).
//   - wave = 64 queries as 2 col-tiles of 32 -> two independent 6-deep MFMA
//     chains per tt
//   - kept from R6 (all verified): fragment-major LDS (0 bank conflicts),
//     TSPLIT=64 XCD chunking, volatile bq loads (regs resident), simple
//     2-barrier tile loop

typedef __attribute__((ext_vector_type(8))) short bf16x8;
typedef __attribute__((ext_vector_type(4))) float f32x4;
typedef __attribute__((ext_vector_type(16))) float f32x16;

#define NQ 8192
#define NT 65536
#define KD 96
#define QB 256            // queries per WG: 4 waves x 64
#define TSPLIT 64         // train chunks; chunk t -> XCD t%8
#define TCHUNK (NT / TSPLIT)   // 1024 rows per WG
#define TTILE 64          // train rows per LDS tile
#define TILES (TCHUNK / TTILE) // 16
#define FRAG_USH 512      // ushorts per (tt,kb) fragment block (64 lanes x 8)

static __device__ __forceinline__ ushort f2bf(float f) {
  unsigned u = __float_as_uint(f);
  return (ushort)((u + 0x7fffu + ((u >> 16) & 1u)) >> 16);
}
static __device__ __forceinline__ unsigned pk2(float a, float b) {
  return (unsigned)f2bf(a) | ((unsigned)f2bf(b) << 16);
}

// Thread t owns float4s [6t, 6t+6) = one quarter-row (96B contiguous).
// Row norm = quad shuffle-reduce (xor 1, xor 2). No LDS, no barriers.
__global__ __launch_bounds__(256) void prep_kernel(
    const float* __restrict__ qf, const float* __restrict__ tf,
    ushort* __restrict__ qbf, ushort* __restrict__ tbf,
    float* __restrict__ x2, float* __restrict__ y2,
    float* __restrict__ outp)
{
  const int tid = threadIdx.x;
  const int b = blockIdx.x;
  const bool isq = b < (NQ / 64);
  const int rb = isq ? b : b - (NQ / 64);
  const float4* src = (const float4*)((isq ? qf : tf) + (size_t)rb * 64 * KD);
  uint2* dst = (uint2*)((isq ? qbf : tbf) + (size_t)rb * 64 * KD);
  const float scale = isq ? 1.0f : -2.0f;

  float s = 0.0f;
  #pragma unroll
  for (int i = 0; i < 6; ++i) {
    float4 v = src[tid * 6 + i];
    s += v.x * v.x + v.y * v.y + v.z * v.z + v.w * v.w;
    uint2 p; p.x = pk2(v.x * scale, v.y * scale); p.y = pk2(v.z * scale, v.w * scale);
    dst[tid * 6 + i] = p;
  }
  s += __shfl_xor(s, 1, 64);
  s += __shfl_xor(s, 2, 64);
  if ((tid & 3) == 0) {
    int row = rb * 64 + (tid >> 2);
    if (isq) { x2[row] = s; outp[row] = __uint_as_float(0x7f800000u); }
    else     { y2[row] = s; }
  }
}

__global__ __launch_bounds__(256, 3) void min_dist_kernel(
    const ushort* __restrict__ qbf, const ushort* __restrict__ tbf,
    const float* __restrict__ x2, const float* __restrict__ y2,
    float* __restrict__ outp)
{
  // fragment-major A tile: frag f = tt*6+kb; 512 ushorts = 64 lanes x 8
  // lane l holds A[row = tt*32 + (l&31)][k = kb*16 + (l>>5)*8 + 0..7]
  __shared__ __align__(16) ushort ldsA[TTILE * KD];   // 12 KB
  __shared__ __align__(16) float ldsY[TTILE];

  const int tid  = threadIdx.x;
  const int w    = tid >> 6;
  const int lane = tid & 63;
  const int col  = lane & 31;
  const int hi   = lane >> 5;
  const int tsplit = blockIdx.x & (TSPLIT - 1);   // -> XCD tsplit%8
  const int qblock = blockIdx.x / TSPLIT;
  const int qbase  = qblock * QB + w * 64;

  // B-operand (query) fragments: 2 col-tiles x 6 k-blocks = 48 VGPRs.
  // B lane layout: col = lane&31, k = kb*16 + hi*8 + 0..7.
  // volatile: forbid the compiler from sinking these loads into the K-loop
  // (R4/R5: it did, VGPR_Count dropped below 48 and the kernel went TCP-bound)
  bf16x8 bq[2][6];
  #pragma unroll
  for (int ct = 0; ct < 2; ++ct) {
    const ushort* qp = qbf + (size_t)(qbase + ct * 32 + col) * KD + hi * 8;
    #pragma unroll
    for (int kb = 0; kb < 6; ++kb)
      bq[ct][kb] = *(const volatile bf16x8*)(qp + kb * 16);
  }

  // staging map: thread stages 3 x 16B chunks, LDS lane-contiguous
  int goff[3], loff[3];
  #pragma unroll
  for (int it = 0; it < 3; ++it) {
    int o = it * 256 + tid;           // 16B chunk id 0..767
    int f = o >> 6;                   // frag id = tt*6+kb (wave-uniform)
    int tt = f / 6, kb = f - tt * 6;
    int l = o & 63;
    goff[it] = (tt * 32 + (l & 31)) * KD + kb * 16 + (l >> 5) * 8;  // ushort
    loff[it] = o * 8;                                                // ushort
  }

  const float INF = __uint_as_float(0x7f800000u);
  float m0 = INF, m1 = INF;

  const int trow0 = tsplit * TCHUNK;

  #pragma unroll 1
  for (int tile = 0; tile < TILES; ++tile) {
    const int tb = trow0 + tile * TTILE;
    const ushort* g = tbf + (size_t)tb * KD;
    __syncthreads();
    #pragma unroll
    for (int it = 0; it < 3; ++it)
      *(uint4*)&ldsA[loff[it]] = *(const uint4*)(g + goff[it]);
    if (tid < 16)
      *(f32x4*)&ldsY[tid * 4] = *(const f32x4*)(y2 + tb + tid * 4);
    __syncthreads();

    #pragma unroll
    for (int tt = 0; tt < 2; ++tt) {
      const ushort* ap = &ldsA[tt * 6 * FRAG_USH + lane * 8];
      bf16x8 a0 = *(const bf16x8*)(ap);
      bf16x8 a1 = *(const bf16x8*)(ap + FRAG_USH);
      bf16x8 a2 = *(const bf16x8*)(ap + 2 * FRAG_USH);
      bf16x8 a3 = *(const bf16x8*)(ap + 3 * FRAG_USH);
      bf16x8 a4 = *(const bf16x8*)(ap + 4 * FRAG_USH);
      bf16x8 a5 = *(const bf16x8*)(ap + 5 * FRAG_USH);

      // C preload: lane row set = {(reg&3) + 8*(reg>>2) + 4*hi} (+tt*32)
      f32x16 y2v;
      #pragma unroll
      for (int q = 0; q < 4; ++q) {
        f32x4 yv = *(const f32x4*)&ldsY[tt * 32 + hi * 4 + q * 8];
        y2v[4 * q + 0] = yv[0];
        y2v[4 * q + 1] = yv[1];
        y2v[4 * q + 2] = yv[2];
        y2v[4 * q + 3] = yv[3];
      }

      // two independent 6-deep chains (col-tiles) over K=96
      f32x16 acc0 = __builtin_amdgcn_mfma_f32_32x32x16_bf16(a0, bq[0][0], y2v, 0, 0, 0);
      f32x16 acc1 = __builtin_amdgcn_mfma_f32_32x32x16_bf16(a0, bq[1][0], y2v, 0, 0, 0);
      acc0 = __builtin_amdgcn_mfma_f32_32x32x16_bf16(a1, bq[0][1], acc0, 0, 0, 0);
      acc1 = __builtin_amdgcn_mfma_f32_32x32x16_bf16(a1, bq[1][1], acc1, 0, 0, 0);
      acc0 = __builtin_amdgcn_mfma_f32_32x32x16_bf16(a2, bq[0][2], acc0, 0, 0, 0);
      acc1 = __builtin_amdgcn_mfma_f32_32x32x16_bf16(a2, bq[1][2], acc1, 0, 0, 0);
      acc0 = __builtin_amdgcn_mfma_f32_32x32x16_bf16(a3, bq[0][3], acc0, 0, 0, 0);
      acc1 = __builtin_amdgcn_mfma_f32_32x32x16_bf16(a3, bq[1][3], acc1, 0, 0, 0);
      acc0 = __builtin_amdgcn_mfma_f32_32x32x16_bf16(a4, bq[0][4], acc0, 0, 0, 0);
      acc1 = __builtin_amdgcn_mfma_f32_32x32x16_bf16(a4, bq[1][4], acc1, 0, 0, 0);
      acc0 = __builtin_amdgcn_mfma_f32_32x32x16_bf16(a5, bq[0][5], acc0, 0, 0, 0);
      acc1 = __builtin_amdgcn_mfma_f32_32x32x16_bf16(a5, bq[1][5], acc1, 0, 0, 0);

      // plain fminf balanced tree (clang may fuse pairs+singles to v_min3)
      {
        float r0 = fminf(fminf(acc0[0],  acc0[1]),  fminf(acc0[2],  acc0[3]));
        float r1 = fminf(fminf(acc0[4],  acc0[5]),  fminf(acc0[6],  acc0[7]));
        float r2 = fminf(fminf(acc0[8],  acc0[9]),  fminf(acc0[10], acc0[11]));
        float r3 = fminf(fminf(acc0[12], acc0[13]), fminf(acc0[14], acc0[15]));
        m0 = fminf(m0, fminf(fminf(r0, r1), fminf(r2, r3)));
      }
      {
        float r0 = fminf(fminf(acc1[0],  acc1[1]),  fminf(acc1[2],  acc1[3]));
        float r1 = fminf(fminf(acc1[4],  acc1[5]),  fminf(acc1[6],  acc1[7]));
        float r2 = fminf(fminf(acc1[8],  acc1[9]),  fminf(acc1[10], acc1[11]));
        float r3 = fminf(fminf(acc1[12], acc1[13]), fminf(acc1[14], acc1[15]));
        m1 = fminf(m1, fminf(fminf(r0, r1), fminf(r2, r3)));
      }
    }
  }

  // fold the two half-wave row groups (hi=0/1 hold different train rows)
  m0 = fminf(m0, __shfl_xor(m0, 32, 64));
  m1 = fminf(m1, __shfl_xor(m1, 32, 64));
  if (hi == 0) {
    int q0 = qbase + col;
    float sq0 = fmaxf(x2[q0] + m0, 0.0f);
    atomicMin((unsigned int*)&outp[q0], __float_as_uint(sqrtf(sq0) * 10.0f));
    int q1 = qbase + 32 + col;
    float sq1 = fmaxf(x2[q1] + m1, 0.0f);
    atomicMin((unsigned int*)&outp[q1], __float_as_uint(sqrtf(sq1) * 10.0f));
  }
}

extern "C" void kernel_launch(void* const* d_in, const int* in_sizes, int n_in,
                              void* d_out, int out_size, void* d_ws, size_t ws_size,
                              hipStream_t stream) {
  const float* qf = (const float*)d_in[0];   // mutation_dist 8192x96
  const float* tf = (const float*)d_in[1];   // train_data   65536x96
  float* outp = (float*)d_out;               // 8192 f32

  ushort* qbf = (ushort*)d_ws;                // 8192*96 bf16
  ushort* tbf = qbf + (size_t)NQ * KD;        // 65536*96 bf16, pre-scaled -2
  float* x2 = (float*)(tbf + (size_t)NT * KD);
  float* y2 = x2 + NQ;

  prep_kernel<<<(NQ + NT) / 64, 256, 0, stream>>>(qf, tf, qbf, tbf, x2, y2, outp);
  min_dist_kernel<<<(NQ / QB) * TSPLIT, 256, 0, stream>>>(qbf, tbf, x2, y2, outp);
}